// Round 1
// baseline (545.167 us; speedup 1.0000x reference)
//
#include <hip/hip_runtime.h>
#include <math.h>

#define T_LEN   16384
#define NBATCH  8
#define CH      32
#define NBLK    6
#define TILE    256          // interior time points per workgroup
#define HALO    63           // sum of dilations 1+2+4+8+16+32
#define NTHR    384          // threads = LDS rows; need >= TILE + 2*HALO = 382
#define LSTRIDE 33           // CH + 1 pad -> bank-conflict-free LDS
#define NTILES  (T_LEN / TILE)   // 64

__global__ __launch_bounds__(NTHR, 3)
void wavenet_main(const float* __restrict__ x,
                  const float* __restrict__ w_init,  const float* __restrict__ b_init,
                  const float* __restrict__ w_tanh,  const float* __restrict__ b_tanh,
                  const float* __restrict__ w_sig,   const float* __restrict__ b_sig,
                  const float* __restrict__ w_skip,  const float* __restrict__ b_skip,
                  const float* __restrict__ w_final, const float* __restrict__ b_final,
                  const float* __restrict__ w_dense,
                  float* __restrict__ logits)
{
    __shared__ float h_lds[NTHR * LSTRIDE];
    __shared__ float red[NTHR / 64][2];

    const int tile = blockIdx.x % NTILES;
    const int b    = blockIdx.x / NTILES;
    const int j    = threadIdx.x;
    const int tg   = tile * TILE - HALO + j;           // global time index
    const bool valid = (tg >= 0) && (tg < T_LEN);

    // ---- init 1x1 conv (CIN=1 -> CH) + relu, into LDS ----
    float xv = valid ? x[(size_t)b * T_LEN + tg] : 0.0f;
    #pragma unroll
    for (int c = 0; c < CH; ++c) {
        float h = fmaxf(fmaf(xv, w_init[c], b_init[c]), 0.0f);
        h_lds[j * LSTRIDE + c] = valid ? h : 0.0f;     // out-of-range stays exactly 0
    }

    float skip_sum[CH];
    #pragma unroll
    for (int c = 0; c < CH; ++c) skip_sum[c] = 0.0f;

    __syncthreads();

    // ---- 6 gated residual blocks ----
    for (int i = 0; i < NBLK; ++i) {
        const int d = 1 << i;
        float acc_t[CH], acc_s[CH];
        #pragma unroll
        for (int c = 0; c < CH; ++c) { acc_t[c] = 0.0f; acc_s[c] = 0.0f; }

        // dilated K=3 convs (tanh branch + sigmoid branch share h reads)
        for (int tap = 0; tap < 3; ++tap) {
            int jn = j + (tap - 1) * d;
            jn = max(0, min(NTHR - 1, jn));            // clamp: only garbage zone affected
            const float* __restrict__ hrow = &h_lds[jn * LSTRIDE];
            const float* __restrict__ wt = &w_tanh[((size_t)(i * 3 + tap)) * CH * CH];
            const float* __restrict__ ws = &w_sig [((size_t)(i * 3 + tap)) * CH * CH];
            for (int cin = 0; cin < CH; ++cin) {
                float hv = hrow[cin];
                #pragma unroll
                for (int c = 0; c < CH; ++c) {
                    acc_t[c] = fmaf(wt[cin * CH + c], hv, acc_t[c]);
                    acc_s[c] = fmaf(ws[cin * CH + c], hv, acc_s[c]);
                }
            }
        }

        // gated activation: tanh * sigmoid
        #pragma unroll
        for (int c = 0; c < CH; ++c) {
            float tv = tanhf(acc_t[c] + b_tanh[i * CH + c]);
            float sv = acc_s[c] + b_sig[i * CH + c];
            float gv = 1.0f / (1.0f + expf(-sv));
            acc_t[c] = tv * gv;                        // acc_t now holds gated value
        }

        // skip 1x1 conv (register-resident input; fully unrolled)
        #pragma unroll
        for (int c = 0; c < CH; ++c) acc_s[c] = 0.0f;
        #pragma unroll
        for (int cin = 0; cin < CH; ++cin) {
            float hv = acc_t[cin];
            const float* __restrict__ wk = &w_skip[((size_t)(i * CH + cin)) * CH];
            #pragma unroll
            for (int c = 0; c < CH; ++c)
                acc_s[c] = fmaf(wk[c], hv, acc_s[c]);
        }

        // relu(skip), residual, skip_sum; h_new into acc_t
        #pragma unroll
        for (int c = 0; c < CH; ++c) {
            float sk = fmaxf(acc_s[c] + b_skip[i * CH + c], 0.0f);
            skip_sum[c] += sk;
            acc_t[c] = sk + h_lds[j * LSTRIDE + c];
        }

        __syncthreads();                               // everyone done reading old h
        #pragma unroll
        for (int c = 0; c < CH; ++c)
            h_lds[j * LSTRIDE + c] = valid ? acc_t[c] : 0.0f;
        __syncthreads();
    }

    // ---- relu(skip_sum) -> final 1x1 conv ----
    float yv[CH];
    #pragma unroll
    for (int c = 0; c < CH; ++c) yv[c] = fmaxf(skip_sum[c], 0.0f);

    float yf[CH];
    #pragma unroll
    for (int c = 0; c < CH; ++c) yf[c] = 0.0f;
    #pragma unroll
    for (int cin = 0; cin < CH; ++cin) {
        float hv = yv[cin];
        const float* __restrict__ wf = &w_final[cin * CH];
        #pragma unroll
        for (int c = 0; c < CH; ++c)
            yf[c] = fmaf(wf[c], hv, yf[c]);
    }

    // ---- partial dot with w_dense (only interior points; always globally valid) ----
    float p0 = 0.0f, p1 = 0.0f;
    const bool interior = (j >= HALO) && (j < HALO + TILE);
    if (interior) {
        const float* __restrict__ wd = &w_dense[(size_t)tg * CH * 2];
        #pragma unroll
        for (int c = 0; c < CH; ++c) {
            float v = fmaxf(yf[c] + b_final[c], 0.0f); // relu(final conv)
            p0 = fmaf(v, wd[2 * c + 0], p0);
            p1 = fmaf(v, wd[2 * c + 1], p1);
        }
    }

    // wave (64) shuffle reduction, then cross-wave via LDS
    #pragma unroll
    for (int off = 32; off > 0; off >>= 1) {
        p0 += __shfl_down(p0, off);
        p1 += __shfl_down(p1, off);
    }
    const int wave = j >> 6;
    if ((j & 63) == 0) { red[wave][0] = p0; red[wave][1] = p1; }
    __syncthreads();
    if (j == 0) {
        float s0 = 0.0f, s1 = 0.0f;
        #pragma unroll
        for (int w = 0; w < NTHR / 64; ++w) { s0 += red[w][0]; s1 += red[w][1]; }
        atomicAdd(&logits[b * 2 + 0], s0);
        atomicAdd(&logits[b * 2 + 1], s1);
    }
}

__global__ void wavenet_softmax(const float* __restrict__ logits,
                                const float* __restrict__ b_dense,
                                float* __restrict__ out)
{
    int b = threadIdx.x;
    if (b < NBATCH) {
        float l0 = logits[b * 2 + 0] + b_dense[0];
        float l1 = logits[b * 2 + 1] + b_dense[1];
        float m  = fmaxf(l0, l1);
        float e0 = expf(l0 - m), e1 = expf(l1 - m);
        float inv = 1.0f / (e0 + e1);
        out[b * 2 + 0] = e0 * inv;
        out[b * 2 + 1] = e1 * inv;
    }
}

extern "C" void kernel_launch(void* const* d_in, const int* in_sizes, int n_in,
                              void* d_out, int out_size, void* d_ws, size_t ws_size,
                              hipStream_t stream) {
    const float* x       = (const float*)d_in[0];
    const float* w_init  = (const float*)d_in[1];
    const float* b_init  = (const float*)d_in[2];
    const float* w_tanh  = (const float*)d_in[3];
    const float* b_tanh  = (const float*)d_in[4];
    const float* w_sig   = (const float*)d_in[5];
    const float* b_sig   = (const float*)d_in[6];
    const float* w_skip  = (const float*)d_in[7];
    const float* b_skip  = (const float*)d_in[8];
    const float* w_final = (const float*)d_in[9];
    const float* b_final = (const float*)d_in[10];
    const float* w_dense = (const float*)d_in[11];
    const float* b_dense = (const float*)d_in[12];

    float* logits = (float*)d_ws;
    hipMemsetAsync(logits, 0, NBATCH * 2 * sizeof(float), stream);

    wavenet_main<<<NBATCH * NTILES, NTHR, 0, stream>>>(
        x, w_init, b_init, w_tanh, b_tanh, w_sig, b_sig,
        w_skip, b_skip, w_final, b_final, w_dense, logits);

    wavenet_softmax<<<1, 64, 0, stream>>>(logits, b_dense, (float*)d_out);
}

// Round 2
// 228.973 us; speedup vs baseline: 2.3809x; 2.3809x over previous
//
#include <hip/hip_runtime.h>
#include <math.h>

#define T_LEN   16384
#define NBATCH  8
#define CH      32
#define NBLK    6
#define TILE    256
#define HALO    63
#define NTHR    384
#define NTILES  64
#define HS      36            // h row stride in dwords (144 B, 16B-aligned, low bank conflicts)

// workspace layout (dwords)
#define WS_CONV 0             // [i6][tap3][nt4][hl2][lane64][dw4] = 36864
#define WS_SKIP 36864         // [i6][nt2][hl2][lane64][dw4]      = 6144
#define WS_FIN  43008         // [nt2][hl2][lane64][dw4]          = 1024
#define WS_LOG  44032         // 16 floats
#define PREP_N  44032

typedef short short8 __attribute__((ext_vector_type(8)));
typedef float f32x4  __attribute__((ext_vector_type(4)));

union F8 { unsigned u[4]; short8 v; };

__device__ __forceinline__ unsigned bf16_rne(float x) {
    unsigned u = __float_as_uint(x);
    return (u + 0x7fffu + ((u >> 16) & 1u)) >> 16;
}
__device__ __forceinline__ unsigned packbf(float x) {
    unsigned hi = bf16_rne(x);
    float fhi = __uint_as_float(hi << 16);
    unsigned lo = bf16_rne(x - fhi);
    return (hi << 16) | lo;
}
__device__ __forceinline__ float uph(unsigned p) { return __uint_as_float(p & 0xffff0000u); }
__device__ __forceinline__ float upl(unsigned p) { return __uint_as_float(p << 16); }

__device__ __forceinline__ short8 mkhi(uint4 q0, uint4 q1) {
    F8 r;
    r.u[0] = __builtin_amdgcn_perm(q0.y, q0.x, 0x07060302u);
    r.u[1] = __builtin_amdgcn_perm(q0.w, q0.z, 0x07060302u);
    r.u[2] = __builtin_amdgcn_perm(q1.y, q1.x, 0x07060302u);
    r.u[3] = __builtin_amdgcn_perm(q1.w, q1.z, 0x07060302u);
    return r.v;
}
__device__ __forceinline__ short8 mklo(uint4 q0, uint4 q1) {
    F8 r;
    r.u[0] = __builtin_amdgcn_perm(q0.y, q0.x, 0x05040100u);
    r.u[1] = __builtin_amdgcn_perm(q0.w, q0.z, 0x05040100u);
    r.u[2] = __builtin_amdgcn_perm(q1.y, q1.x, 0x05040100u);
    r.u[3] = __builtin_amdgcn_perm(q1.w, q1.z, 0x05040100u);
    return r.v;
}

__device__ __forceinline__ float sig_fast(float x) {
    return __builtin_amdgcn_rcpf(1.0f + __expf(-x));
}
__device__ __forceinline__ float tanh_fast(float x) {
    return fmaf(2.0f, sig_fast(2.0f * x), -1.0f);
}
__device__ __forceinline__ float relu(float x) { return fmaxf(x, 0.0f); }

#define MFMA(a, b, c) __builtin_amdgcn_mfma_f32_16x16x32_bf16((a), (b), (c), 0, 0, 0)

// ---------------- weight prep: fp32 -> bf16 hi/lo B-fragments ----------------
__device__ __forceinline__ unsigned cvt16(float v, int hl) {
    unsigned hi = bf16_rne(v);
    if (hl == 0) return hi;
    return bf16_rne(v - __uint_as_float(hi << 16));
}

__global__ void wavenet_prep(const float* __restrict__ wt, const float* __restrict__ wsg,
                             const float* __restrict__ wsk, const float* __restrict__ wfin,
                             unsigned* __restrict__ out)
{
    int id = blockIdx.x * 256 + threadIdx.x;
    if (id >= PREP_N) return;
    int dw = id & 3, lane = (id >> 2) & 63;
    int g = lane >> 4, nlo = lane & 15;
    int e0 = dw * 2, e1 = dw * 2 + 1;
    float v0, v1; int hl;
    if (id < WS_SKIP) {
        hl = (id >> 8) & 1; int nt = (id >> 9) & 3; int q = id >> 11;
        int tap = q % 3, i = q / 3;
        int n = nt * 16 + nlo;
        const float* src = (n < 32) ? wt : wsg;
        int nn = (n < 32) ? n : n - 32;
        v0 = src[(((i * 3 + tap) * 32) + g * 8 + e0) * 32 + nn];
        v1 = src[(((i * 3 + tap) * 32) + g * 8 + e1) * 32 + nn];
    } else if (id < WS_FIN) {
        int t = id - WS_SKIP;
        hl = (t >> 8) & 1; int nt = (t >> 9) & 1; int i = t >> 10;
        int n = nt * 16 + nlo;
        v0 = wsk[((i * 32) + g * 8 + e0) * 32 + n];
        v1 = wsk[((i * 32) + g * 8 + e1) * 32 + n];
    } else {
        int t = id - WS_FIN;
        hl = (t >> 8) & 1; int nt = (t >> 9) & 1;
        int n = nt * 16 + nlo;
        v0 = wfin[(g * 8 + e0) * 32 + n];
        v1 = wfin[(g * 8 + e1) * 32 + n];
    }
    out[id] = (cvt16(v1, hl) << 16) | cvt16(v0, hl);
}

// ---------------- main fused kernel ----------------
__global__ __launch_bounds__(NTHR, 3)
void wavenet_main(const float* __restrict__ x,
                  const float* __restrict__ w_init, const float* __restrict__ b_init,
                  const float* __restrict__ b_tanh, const float* __restrict__ b_sig,
                  const float* __restrict__ b_skip, const float* __restrict__ b_final,
                  const float* __restrict__ w_dense,
                  const unsigned* __restrict__ wsB,
                  float* __restrict__ logits)
{
    __shared__ unsigned h_pack[NTHR * HS];     // 55296 B
    __shared__ unsigned z_pack[6 * 16 * HS];   // 13824 B
    __shared__ float red[6][2];

    const int tid  = threadIdx.x;
    const int lane = tid & 63;
    const int wv   = tid >> 6;
    const int tile = blockIdx.x & (NTILES - 1);
    const int b    = blockIdx.x >> 6;
    const int col0 = lane & 15;
    const int g4   = lane >> 4;

    // ---- init conv (CIN=1) -> packed hi/lo h in LDS ----
    {
        int j = tid;
        int tg = tile * TILE - HALO + j;
        bool valid = (tg >= 0) && (tg < T_LEN);
        float xv = valid ? x[(size_t)b * T_LEN + tg] : 0.0f;
        unsigned* hp = &h_pack[j * HS];
        #pragma unroll
        for (int q = 0; q < 8; ++q) {
            uint4 pk;
            pk.x = valid ? packbf(relu(fmaf(xv, w_init[4 * q + 0], b_init[4 * q + 0]))) : 0u;
            pk.y = valid ? packbf(relu(fmaf(xv, w_init[4 * q + 1], b_init[4 * q + 1]))) : 0u;
            pk.z = valid ? packbf(relu(fmaf(xv, w_init[4 * q + 2], b_init[4 * q + 2]))) : 0u;
            pk.w = valid ? packbf(relu(fmaf(xv, w_init[4 * q + 3], b_init[4 * q + 3]))) : 0u;
            *(uint4*)(hp + 4 * q) = pk;
        }
    }
    __syncthreads();

    float sksum0[4][4], sksum1[4][4];
    #pragma unroll
    for (int mt = 0; mt < 4; ++mt)
        #pragma unroll
        for (int r = 0; r < 4; ++r) { sksum0[mt][r] = 0.0f; sksum1[mt][r] = 0.0f; }

    for (int i = 0; i < NBLK; ++i) {
        const int d = 1 << i;
        f32x4 acc[4][4];
        #pragma unroll
        for (int mt = 0; mt < 4; ++mt)
            #pragma unroll
            for (int nt = 0; nt < 4; ++nt) acc[mt][nt] = (f32x4){0.f, 0.f, 0.f, 0.f};

        // conv GEMM: [384 x 96] x [96 x 64]  (bf16 hi/lo, 3-product split)
        #pragma unroll
        for (int tap = 0; tap < 3; ++tap) {
            short8 bh[4], bl[4];
            #pragma unroll
            for (int nt = 0; nt < 4; ++nt) {
                const unsigned* bp = wsB + (((i * 3 + tap) * 4 + nt) * 2) * 256 + lane * 4;
                bh[nt] = *(const short8*)bp;
                bl[nt] = *(const short8*)(bp + 256);
            }
            int rb = wv * 64 + (tap - 1) * d + col0;
            #pragma unroll
            for (int mt = 0; mt < 4; ++mt) {
                int r = rb + 16 * mt;
                r = r < 0 ? 0 : (r > NTHR - 1 ? NTHR - 1 : r);
                const unsigned* hp = &h_pack[r * HS + g4 * 8];
                uint4 q0 = *(const uint4*)hp;
                uint4 q1 = *(const uint4*)(hp + 4);
                short8 ah = mkhi(q0, q1), al = mklo(q0, q1);
                #pragma unroll
                for (int nt = 0; nt < 4; ++nt) {
                    acc[mt][nt] = MFMA(ah, bh[nt], acc[mt][nt]);
                    acc[mt][nt] = MFMA(ah, bl[nt], acc[mt][nt]);
                    acc[mt][nt] = MFMA(al, bh[nt], acc[mt][nt]);
                }
            }
        }
        __syncthreads();   // all conv reads of h done

        float bt0 = b_tanh[i * 32 + col0], bt1 = b_tanh[i * 32 + col0 + 16];
        float bs0 = b_sig [i * 32 + col0], bs1 = b_sig [i * 32 + col0 + 16];
        float bk0 = b_skip[i * 32 + col0], bk1 = b_skip[i * 32 + col0 + 16];
        short8 skh[2], skl[2];
        #pragma unroll
        for (int nt = 0; nt < 2; ++nt) {
            const unsigned* bp = wsB + WS_SKIP + ((i * 2 + nt) * 2) * 256 + lane * 4;
            skh[nt] = *(const short8*)bp;
            skl[nt] = *(const short8*)(bp + 256);
        }
        unsigned* zb = &z_pack[wv * 16 * HS];

        #pragma unroll
        for (int mt = 0; mt < 4; ++mt) {
            // gated activation -> z (packed hi/lo) into wave-local LDS
            #pragma unroll
            for (int reg = 0; reg < 4; ++reg) {
                float z0 = tanh_fast(acc[mt][0][reg] + bt0) * sig_fast(acc[mt][2][reg] + bs0);
                float z1 = tanh_fast(acc[mt][1][reg] + bt1) * sig_fast(acc[mt][3][reg] + bs1);
                unsigned* zp = zb + (4 * g4 + reg) * HS + col0;
                zp[0]  = packbf(z0);
                zp[16] = packbf(z1);
            }
            asm volatile("s_waitcnt lgkmcnt(0)" ::: "memory");
            // z as A-fragments (wave-local, no barrier needed)
            const unsigned* za = zb + col0 * HS + g4 * 8;
            uint4 zq0 = *(const uint4*)za;
            uint4 zq1 = *(const uint4*)(za + 4);
            short8 azh = mkhi(zq0, zq1), azl = mklo(zq0, zq1);
            f32x4 s0 = (f32x4){0.f, 0.f, 0.f, 0.f}, s1 = (f32x4){0.f, 0.f, 0.f, 0.f};
            s0 = MFMA(azh, skh[0], s0); s0 = MFMA(azh, skl[0], s0); s0 = MFMA(azl, skh[0], s0);
            s1 = MFMA(azh, skh[1], s1); s1 = MFMA(azh, skl[1], s1); s1 = MFMA(azl, skh[1], s1);
            // skip epilogue + residual
            #pragma unroll
            for (int reg = 0; reg < 4; ++reg) {
                int row = wv * 64 + 16 * mt + 4 * g4 + reg;
                int tgr = tile * TILE - HALO + row;
                bool vr = (tgr >= 0) && (tgr < T_LEN);
                float sk0 = relu(s0[reg] + bk0);
                float sk1 = relu(s1[reg] + bk1);
                sksum0[mt][reg] += sk0;
                sksum1[mt][reg] += sk1;
                if (i != NBLK - 1) {
                    unsigned* hp2 = &h_pack[row * HS + col0];
                    unsigned p0 = hp2[0], p1 = hp2[16];
                    float h0 = sk0 + uph(p0) + upl(p0);
                    float h1 = sk1 + uph(p1) + upl(p1);
                    hp2[0]  = vr ? packbf(h0) : 0u;
                    hp2[16] = vr ? packbf(h1) : 0u;
                }
            }
        }
        __syncthreads();   // h updates visible before next iter's conv
    }

    // ---- y = relu(skip_sum) -> h region (own rows), then final conv via MFMA ----
    #pragma unroll
    for (int mt = 0; mt < 4; ++mt)
        #pragma unroll
        for (int reg = 0; reg < 4; ++reg) {
            int row = wv * 64 + 16 * mt + 4 * g4 + reg;
            unsigned* hp2 = &h_pack[row * HS + col0];
            hp2[0]  = packbf(relu(sksum0[mt][reg]));
            hp2[16] = packbf(relu(sksum1[mt][reg]));
        }
    asm volatile("s_waitcnt lgkmcnt(0)" ::: "memory");

    short8 fh[2], fl[2];
    #pragma unroll
    for (int nt = 0; nt < 2; ++nt) {
        const unsigned* bp = wsB + WS_FIN + (nt * 2) * 256 + lane * 4;
        fh[nt] = *(const short8*)bp;
        fl[nt] = *(const short8*)(bp + 256);
    }
    float bf0 = b_final[col0], bf1 = b_final[col0 + 16];
    float pa = 0.0f, pb = 0.0f;

    #pragma unroll
    for (int mt = 0; mt < 4; ++mt) {
        const unsigned* ya = &h_pack[(wv * 64 + 16 * mt + col0) * HS + g4 * 8];
        uint4 yq0 = *(const uint4*)ya;
        uint4 yq1 = *(const uint4*)(ya + 4);
        short8 ayh = mkhi(yq0, yq1), ayl = mklo(yq0, yq1);
        f32x4 f0 = (f32x4){0.f, 0.f, 0.f, 0.f}, f1 = (f32x4){0.f, 0.f, 0.f, 0.f};
        f0 = MFMA(ayh, fh[0], f0); f0 = MFMA(ayh, fl[0], f0); f0 = MFMA(ayl, fh[0], f0);
        f1 = MFMA(ayh, fh[1], f1); f1 = MFMA(ayh, fl[1], f1); f1 = MFMA(ayl, fh[1], f1);
        #pragma unroll
        for (int reg = 0; reg < 4; ++reg) {
            int row = wv * 64 + 16 * mt + 4 * g4 + reg;
            if (row >= HALO && row < HALO + TILE) {
                int tgr = tile * TILE - HALO + row;
                float v0 = relu(f0[reg] + bf0);
                float v1 = relu(f1[reg] + bf1);
                const float* wd0 = w_dense + ((size_t)tgr * 32 + col0) * 2;
                const float* wd1 = w_dense + ((size_t)tgr * 32 + col0 + 16) * 2;
                pa = fmaf(v0, wd0[0], pa); pb = fmaf(v0, wd0[1], pb);
                pa = fmaf(v1, wd1[0], pa); pb = fmaf(v1, wd1[1], pb);
            }
        }
    }

    // block reduction -> logits
    #pragma unroll
    for (int off = 32; off > 0; off >>= 1) {
        pa += __shfl_down(pa, off);
        pb += __shfl_down(pb, off);
    }
    if (lane == 0) { red[wv][0] = pa; red[wv][1] = pb; }
    __syncthreads();
    if (tid == 0) {
        float s0 = 0.0f, s1 = 0.0f;
        #pragma unroll
        for (int w = 0; w < 6; ++w) { s0 += red[w][0]; s1 += red[w][1]; }
        atomicAdd(&logits[b * 2 + 0], s0);
        atomicAdd(&logits[b * 2 + 1], s1);
    }
}

__global__ void wavenet_softmax(const float* __restrict__ logits,
                                const float* __restrict__ b_dense,
                                float* __restrict__ out)
{
    int b = threadIdx.x;
    if (b < NBATCH) {
        float l0 = logits[b * 2 + 0] + b_dense[0];
        float l1 = logits[b * 2 + 1] + b_dense[1];
        float m  = fmaxf(l0, l1);
        float e0 = __expf(l0 - m), e1 = __expf(l1 - m);
        float inv = __builtin_amdgcn_rcpf(e0 + e1);
        out[b * 2 + 0] = e0 * inv;
        out[b * 2 + 1] = e1 * inv;
    }
}

extern "C" void kernel_launch(void* const* d_in, const int* in_sizes, int n_in,
                              void* d_out, int out_size, void* d_ws, size_t ws_size,
                              hipStream_t stream) {
    const float* x       = (const float*)d_in[0];
    const float* w_init  = (const float*)d_in[1];
    const float* b_init  = (const float*)d_in[2];
    const float* w_tanh  = (const float*)d_in[3];
    const float* b_tanh  = (const float*)d_in[4];
    const float* w_sig   = (const float*)d_in[5];
    const float* b_sig   = (const float*)d_in[6];
    const float* w_skip  = (const float*)d_in[7];
    const float* b_skip  = (const float*)d_in[8];
    const float* w_final = (const float*)d_in[9];
    const float* b_final = (const float*)d_in[10];
    const float* w_dense = (const float*)d_in[11];
    const float* b_dense = (const float*)d_in[12];

    unsigned* wsB   = (unsigned*)d_ws;
    float* logits   = (float*)d_ws + WS_LOG;

    hipMemsetAsync(logits, 0, NBATCH * 2 * sizeof(float), stream);
    wavenet_prep<<<(PREP_N + 255) / 256, 256, 0, stream>>>(w_tanh, w_sig, w_skip, w_final, wsB);
    wavenet_main<<<NBATCH * NTILES, NTHR, 0, stream>>>(
        x, w_init, b_init, b_tanh, b_sig, b_skip, b_final, w_dense, wsB, logits);
    wavenet_softmax<<<1, 64, 0, stream>>>(logits, b_dense, (float*)d_out);
}

// Round 3
// 211.742 us; speedup vs baseline: 2.5747x; 1.0814x over previous
//
#include <hip/hip_runtime.h>
#include <math.h>

#define T_LEN   16384
#define NBATCH  8
#define CH      32
#define NBLK    6
#define TILE    256
#define HALO    63
#define NTHR    384
#define NTILES  64
#define HS      36            // h row stride in dwords (144 B, 16B-aligned)

// workspace layout (dwords)
#define WS_CONV 0             // [i6][tap3][nt4][hl2][lane64][dw4] = 36864
#define WS_SKIP 36864         // [i6][nt2][hl2][lane64][dw4]      = 6144
#define WS_FIN  43008         // [nt2][hl2][lane64][dw4]          = 1024
#define WS_LOG  44032         // 16 floats
#define PREP_N  44032

typedef short short8 __attribute__((ext_vector_type(8)));
typedef float f32x4  __attribute__((ext_vector_type(4)));

union F8 { unsigned u[4]; short8 v; };

__device__ __forceinline__ unsigned bf16_rne(float x) {
    unsigned u = __float_as_uint(x);
    return (u + 0x7fffu + ((u >> 16) & 1u)) >> 16;
}
__device__ __forceinline__ unsigned packbf(float x) {
    unsigned hi = bf16_rne(x);
    float fhi = __uint_as_float(hi << 16);
    unsigned lo = bf16_rne(x - fhi);
    return (hi << 16) | lo;
}
__device__ __forceinline__ float uph(unsigned p) { return __uint_as_float(p & 0xffff0000u); }
__device__ __forceinline__ float upl(unsigned p) { return __uint_as_float(p << 16); }

__device__ __forceinline__ short8 mkhi(uint4 q0, uint4 q1) {
    F8 r;
    r.u[0] = __builtin_amdgcn_perm(q0.y, q0.x, 0x07060302u);
    r.u[1] = __builtin_amdgcn_perm(q0.w, q0.z, 0x07060302u);
    r.u[2] = __builtin_amdgcn_perm(q1.y, q1.x, 0x07060302u);
    r.u[3] = __builtin_amdgcn_perm(q1.w, q1.z, 0x07060302u);
    return r.v;
}
__device__ __forceinline__ short8 mklo(uint4 q0, uint4 q1) {
    F8 r;
    r.u[0] = __builtin_amdgcn_perm(q0.y, q0.x, 0x05040100u);
    r.u[1] = __builtin_amdgcn_perm(q0.w, q0.z, 0x05040100u);
    r.u[2] = __builtin_amdgcn_perm(q1.y, q1.x, 0x05040100u);
    r.u[3] = __builtin_amdgcn_perm(q1.w, q1.z, 0x05040100u);
    return r.v;
}

__device__ __forceinline__ float sig_fast(float x) {
    return __builtin_amdgcn_rcpf(1.0f + __expf(-x));
}
__device__ __forceinline__ float tanh_fast(float x) {
    return fmaf(2.0f, sig_fast(2.0f * x), -1.0f);
}
__device__ __forceinline__ float relu(float x) { return fmaxf(x, 0.0f); }

#define MFMA(a, b, c) __builtin_amdgcn_mfma_f32_16x16x32_bf16((a), (b), (c), 0, 0, 0)

// ---------------- weight prep: fp32 -> bf16 hi/lo B-fragments ----------------
__device__ __forceinline__ unsigned cvt16(float v, int hl) {
    unsigned hi = bf16_rne(v);
    if (hl == 0) return hi;
    return bf16_rne(v - __uint_as_float(hi << 16));
}

__global__ void wavenet_prep(const float* __restrict__ wt, const float* __restrict__ wsg,
                             const float* __restrict__ wsk, const float* __restrict__ wfin,
                             unsigned* __restrict__ out)
{
    int id = blockIdx.x * 256 + threadIdx.x;
    if (id >= PREP_N) return;
    int dw = id & 3, lane = (id >> 2) & 63;
    int g = lane >> 4, nlo = lane & 15;
    int e0 = dw * 2, e1 = dw * 2 + 1;
    float v0, v1; int hl;
    if (id < WS_SKIP) {
        hl = (id >> 8) & 1; int nt = (id >> 9) & 3; int q = id >> 11;
        int tap = q % 3, i = q / 3;
        int n = nt * 16 + nlo;
        const float* src = (n < 32) ? wt : wsg;
        int nn = (n < 32) ? n : n - 32;
        v0 = src[(((i * 3 + tap) * 32) + g * 8 + e0) * 32 + nn];
        v1 = src[(((i * 3 + tap) * 32) + g * 8 + e1) * 32 + nn];
    } else if (id < WS_FIN) {
        int t = id - WS_SKIP;
        hl = (t >> 8) & 1; int nt = (t >> 9) & 1; int i = t >> 10;
        int n = nt * 16 + nlo;
        v0 = wsk[((i * 32) + g * 8 + e0) * 32 + n];
        v1 = wsk[((i * 32) + g * 8 + e1) * 32 + n];
    } else {
        int t = id - WS_FIN;
        hl = (t >> 8) & 1; int nt = (t >> 9) & 1;
        int n = nt * 16 + nlo;
        v0 = wfin[(g * 8 + e0) * 32 + n];
        v1 = wfin[(g * 8 + e1) * 32 + n];
    }
    out[id] = (cvt16(v1, hl) << 16) | cvt16(v0, hl);
}

// ---------------- main fused kernel ----------------
__global__ __launch_bounds__(NTHR, 3)
void wavenet_main(const float* __restrict__ x,
                  const float* __restrict__ w_init, const float* __restrict__ b_init,
                  const float* __restrict__ b_tanh, const float* __restrict__ b_sig,
                  const float* __restrict__ b_skip, const float* __restrict__ b_final,
                  const float* __restrict__ w_dense,
                  const unsigned* __restrict__ wsB,
                  float* __restrict__ logits)
{
    __shared__ unsigned h_pack[NTHR * HS];     // 55296 B
    __shared__ unsigned z_pack[6 * 16 * HS];   // 13824 B
    __shared__ float x_s[NTHR];                // 1536 B
    __shared__ float red[6][2];

    const int tid  = threadIdx.x;
    const int lane = tid & 63;
    const int wv   = tid >> 6;
    const int tile = blockIdx.x & (NTILES - 1);
    const int b    = blockIdx.x >> 6;
    const int col0 = lane & 15;
    const int g4   = lane >> 4;

    // w_init/b_init for this lane's two output channels (for h0 recompute)
    const float wi0 = w_init[col0],      wi1 = w_init[col0 + 16];
    const float bi0 = b_init[col0],      bi1 = b_init[col0 + 16];

    // ---- init conv (CIN=1) -> packed hi/lo h in LDS ----
    {
        int j = tid;
        int tg = tile * TILE - HALO + j;
        bool valid = (tg >= 0) && (tg < T_LEN);
        float xv = valid ? x[(size_t)b * T_LEN + tg] : 0.0f;
        x_s[j] = xv;
        unsigned* hp = &h_pack[j * HS];
        #pragma unroll
        for (int q = 0; q < 8; ++q) {
            uint4 pk;
            pk.x = valid ? packbf(relu(fmaf(xv, w_init[4 * q + 0], b_init[4 * q + 0]))) : 0u;
            pk.y = valid ? packbf(relu(fmaf(xv, w_init[4 * q + 1], b_init[4 * q + 1]))) : 0u;
            pk.z = valid ? packbf(relu(fmaf(xv, w_init[4 * q + 2], b_init[4 * q + 2]))) : 0u;
            pk.w = valid ? packbf(relu(fmaf(xv, w_init[4 * q + 3], b_init[4 * q + 3]))) : 0u;
            *(uint4*)(hp + 4 * q) = pk;
        }
    }
    __syncthreads();

    for (int i = 0; i < NBLK; ++i) {
        const int d = 1 << i;
        f32x4 acc[4][4];
        #pragma unroll
        for (int mt = 0; mt < 4; ++mt)
            #pragma unroll
            for (int nt = 0; nt < 4; ++nt) acc[mt][nt] = (f32x4){0.f, 0.f, 0.f, 0.f};

        // conv GEMM: [384 x 96] x [96 x 64]  (bf16 hi/lo, 3-product split)
        #pragma unroll
        for (int tap = 0; tap < 3; ++tap) {
            short8 bh[4], bl[4];
            #pragma unroll
            for (int nt = 0; nt < 4; ++nt) {
                const unsigned* bp = wsB + (((i * 3 + tap) * 4 + nt) * 2) * 256 + lane * 4;
                bh[nt] = *(const short8*)bp;
                bl[nt] = *(const short8*)(bp + 256);
            }
            int rb = wv * 64 + (tap - 1) * d + col0;
            #pragma unroll
            for (int mt = 0; mt < 4; ++mt) {
                int r = rb + 16 * mt;
                r = r < 0 ? 0 : (r > NTHR - 1 ? NTHR - 1 : r);
                const unsigned* hp = &h_pack[r * HS + g4 * 8];
                uint4 q0 = *(const uint4*)hp;
                uint4 q1 = *(const uint4*)(hp + 4);
                short8 ah = mkhi(q0, q1), al = mklo(q0, q1);
                #pragma unroll
                for (int nt = 0; nt < 4; ++nt) {
                    acc[mt][nt] = MFMA(ah, bh[nt], acc[mt][nt]);
                    acc[mt][nt] = MFMA(ah, bl[nt], acc[mt][nt]);
                    acc[mt][nt] = MFMA(al, bh[nt], acc[mt][nt]);
                }
            }
        }
        __syncthreads();   // all conv reads of h done

        float bt0 = b_tanh[i * 32 + col0], bt1 = b_tanh[i * 32 + col0 + 16];
        float bs0 = b_sig [i * 32 + col0], bs1 = b_sig [i * 32 + col0 + 16];
        float bk0 = b_skip[i * 32 + col0], bk1 = b_skip[i * 32 + col0 + 16];
        short8 skh[2], skl[2];
        #pragma unroll
        for (int nt = 0; nt < 2; ++nt) {
            const unsigned* bp = wsB + WS_SKIP + ((i * 2 + nt) * 2) * 256 + lane * 4;
            skh[nt] = *(const short8*)bp;
            skl[nt] = *(const short8*)(bp + 256);
        }
        unsigned* zb = &z_pack[wv * 16 * HS];

        #pragma unroll
        for (int mt = 0; mt < 4; ++mt) {
            // gated activation -> z (packed hi/lo) into wave-local LDS
            #pragma unroll
            for (int reg = 0; reg < 4; ++reg) {
                float z0 = tanh_fast(acc[mt][0][reg] + bt0) * sig_fast(acc[mt][2][reg] + bs0);
                float z1 = tanh_fast(acc[mt][1][reg] + bt1) * sig_fast(acc[mt][3][reg] + bs1);
                unsigned* zp = zb + (4 * g4 + reg) * HS + col0;
                zp[0]  = packbf(z0);
                zp[16] = packbf(z1);
            }
            asm volatile("s_waitcnt lgkmcnt(0)" ::: "memory");
            // z as A-fragments (wave-local, no barrier needed)
            const unsigned* za = zb + col0 * HS + g4 * 8;
            uint4 zq0 = *(const uint4*)za;
            uint4 zq1 = *(const uint4*)(za + 4);
            short8 azh = mkhi(zq0, zq1), azl = mklo(zq0, zq1);
            f32x4 s0 = (f32x4){0.f, 0.f, 0.f, 0.f}, s1 = (f32x4){0.f, 0.f, 0.f, 0.f};
            s0 = MFMA(azh, skh[0], s0); s0 = MFMA(azh, skl[0], s0); s0 = MFMA(azl, skh[0], s0);
            s1 = MFMA(azh, skh[1], s1); s1 = MFMA(azh, skl[1], s1); s1 = MFMA(azl, skh[1], s1);
            // skip epilogue + residual (telescope: skip_sum = h6 - h0)
            #pragma unroll
            for (int reg = 0; reg < 4; ++reg) {
                int row = wv * 64 + 16 * mt + 4 * g4 + reg;
                int tgr = tile * TILE - HALO + row;
                bool vr = (tgr >= 0) && (tgr < T_LEN);
                float sk0 = relu(s0[reg] + bk0);
                float sk1 = relu(s1[reg] + bk1);
                unsigned* hp2 = &h_pack[row * HS + col0];
                unsigned p0 = hp2[0], p1 = hp2[16];
                float h0n = sk0 + uph(p0) + upl(p0);   // h_{i+1}
                float h1n = sk1 + uph(p1) + upl(p1);
                if (i != NBLK - 1) {
                    hp2[0]  = vr ? packbf(h0n) : 0u;
                    hp2[16] = vr ? packbf(h1n) : 0u;
                } else {
                    // y = relu(skip_sum) = relu(h6 - h_init); h_init recomputed from x
                    float xr  = x_s[row];
                    float hi0 = relu(fmaf(xr, wi0, bi0));
                    float hi1 = relu(fmaf(xr, wi1, bi1));
                    hp2[0]  = packbf(relu(h0n - hi0));
                    hp2[16] = packbf(relu(h1n - hi1));
                }
            }
        }
        __syncthreads();   // h updates visible before next iter's conv
    }

    // ---- final 1x1 conv via MFMA on y (already packed in h_pack) ----
    short8 fh[2], fl[2];
    #pragma unroll
    for (int nt = 0; nt < 2; ++nt) {
        const unsigned* bp = wsB + WS_FIN + (nt * 2) * 256 + lane * 4;
        fh[nt] = *(const short8*)bp;
        fl[nt] = *(const short8*)(bp + 256);
    }
    float bf0 = b_final[col0], bf1 = b_final[col0 + 16];
    float pa = 0.0f, pb = 0.0f;

    #pragma unroll
    for (int mt = 0; mt < 4; ++mt) {
        const unsigned* ya = &h_pack[(wv * 64 + 16 * mt + col0) * HS + g4 * 8];
        uint4 yq0 = *(const uint4*)ya;
        uint4 yq1 = *(const uint4*)(ya + 4);
        short8 ayh = mkhi(yq0, yq1), ayl = mklo(yq0, yq1);
        f32x4 f0 = (f32x4){0.f, 0.f, 0.f, 0.f}, f1 = (f32x4){0.f, 0.f, 0.f, 0.f};
        f0 = MFMA(ayh, fh[0], f0); f0 = MFMA(ayh, fl[0], f0); f0 = MFMA(ayl, fh[0], f0);
        f1 = MFMA(ayh, fh[1], f1); f1 = MFMA(ayh, fl[1], f1); f1 = MFMA(ayl, fh[1], f1);
        #pragma unroll
        for (int reg = 0; reg < 4; ++reg) {
            int row = wv * 64 + 16 * mt + 4 * g4 + reg;
            if (row >= HALO && row < HALO + TILE) {
                int tgr = tile * TILE - HALO + row;
                float v0 = relu(f0[reg] + bf0);
                float v1 = relu(f1[reg] + bf1);
                const float* wd0 = w_dense + ((size_t)tgr * 32 + col0) * 2;
                const float* wd1 = w_dense + ((size_t)tgr * 32 + col0 + 16) * 2;
                pa = fmaf(v0, wd0[0], pa); pb = fmaf(v0, wd0[1], pb);
                pa = fmaf(v1, wd1[0], pa); pb = fmaf(v1, wd1[1], pb);
            }
        }
    }

    // block reduction -> logits
    #pragma unroll
    for (int off = 32; off > 0; off >>= 1) {
        pa += __shfl_down(pa, off);
        pb += __shfl_down(pb, off);
    }
    if (lane == 0) { red[wv][0] = pa; red[wv][1] = pb; }
    __syncthreads();
    if (tid == 0) {
        float s0 = 0.0f, s1 = 0.0f;
        #pragma unroll
        for (int w = 0; w < 6; ++w) { s0 += red[w][0]; s1 += red[w][1]; }
        atomicAdd(&logits[b * 2 + 0], s0);
        atomicAdd(&logits[b * 2 + 1], s1);
    }
}

__global__ void wavenet_softmax(const float* __restrict__ logits,
                                const float* __restrict__ b_dense,
                                float* __restrict__ out)
{
    int b = threadIdx.x;
    if (b < NBATCH) {
        float l0 = logits[b * 2 + 0] + b_dense[0];
        float l1 = logits[b * 2 + 1] + b_dense[1];
        float m  = fmaxf(l0, l1);
        float e0 = __expf(l0 - m), e1 = __expf(l1 - m);
        float inv = __builtin_amdgcn_rcpf(e0 + e1);
        out[b * 2 + 0] = e0 * inv;
        out[b * 2 + 1] = e1 * inv;
    }
}

extern "C" void kernel_launch(void* const* d_in, const int* in_sizes, int n_in,
                              void* d_out, int out_size, void* d_ws, size_t ws_size,
                              hipStream_t stream) {
    const float* x       = (const float*)d_in[0];
    const float* w_init  = (const float*)d_in[1];
    const float* b_init  = (const float*)d_in[2];
    const float* w_tanh  = (const float*)d_in[3];
    const float* b_tanh  = (const float*)d_in[4];
    const float* w_sig   = (const float*)d_in[5];
    const float* b_sig   = (const float*)d_in[6];
    const float* w_skip  = (const float*)d_in[7];
    const float* b_skip  = (const float*)d_in[8];
    const float* w_final = (const float*)d_in[9];
    const float* b_final = (const float*)d_in[10];
    const float* w_dense = (const float*)d_in[11];
    const float* b_dense = (const float*)d_in[12];

    unsigned* wsB   = (unsigned*)d_ws;
    float* logits   = (float*)d_ws + WS_LOG;

    hipMemsetAsync(logits, 0, NBATCH * 2 * sizeof(float), stream);
    wavenet_prep<<<(PREP_N + 255) / 256, 256, 0, stream>>>(w_tanh, w_sig, w_skip, w_final, wsB);
    wavenet_main<<<NBATCH * NTILES, NTHR, 0, stream>>>(
        x, w_init, b_init, b_tanh, b_sig, b_skip, b_final, w_dense, wsB, logits);
    wavenet_softmax<<<1, 64, 0, stream>>>(logits, b_dense, (float*)d_out);
}